// Round 11
// baseline (109.886 us; speedup 1.0000x reference)
//
#include <hip/hip_runtime.h>
#include <math.h>

// Problem constants (fixed by the reference setup)
constexpr int N = 4096;
constexpr int E = 128;
constexpr int H = 8;
constexpr int D = 16;      // E / H
constexpr int SPAN = 50;
constexpr int NBLK = 256;  // 256 blocks <= 256 CUs: co-residency guaranteed

// 16 FMAs: a[c] += x[j] * wj[c]
__device__ __forceinline__ void fma4x4(const float4 x, const float4 w0,
                                       const float4 w1, const float4 w2,
                                       const float4 w3, float4& a)
{
    a.x = fmaf(x.x, w0.x, a.x); a.y = fmaf(x.x, w0.y, a.y);
    a.z = fmaf(x.x, w0.z, a.z); a.w = fmaf(x.x, w0.w, a.w);
    a.x = fmaf(x.y, w1.x, a.x); a.y = fmaf(x.y, w1.y, a.y);
    a.z = fmaf(x.y, w1.z, a.z); a.w = fmaf(x.y, w1.w, a.w);
    a.x = fmaf(x.z, w2.x, a.x); a.y = fmaf(x.z, w2.y, a.y);
    a.z = fmaf(x.z, w2.z, a.z); a.w = fmaf(x.z, w2.w, a.w);
    a.x = fmaf(x.w, w3.x, a.x); a.y = fmaf(x.w, w3.y, a.y);
    a.z = fmaf(x.w, w3.z, a.z); a.w = fmaf(x.w, w3.w, a.w);
}

// ---------------------------------------------------------------------------
// Single fused kernel, 256 blocks x 256 threads, block owns 16 rows.
// Dynamic LDS 68480 B -> 2 blocks/CU possible; 256 blocks always co-resident.
//
// LDS float offsets:
//   qs   [    0, 2048)  q tile 16x128 (persists)
//   bs   [ 2048, 4096)  b-query tile 16x128 (persists)
//   ew   [ 4096, 4512)  per-wave exp weights 4x104
//   at   [ 4512, 6624)  attn tile 16x132
//   big  [ 6624,17120):
//     phase1: xs 3x16x128 @6624, ab 128 @12768, part 2x16x132 @12896
//     phase3: vt 4x[128][17] @6624
//     out   : pO 2x16x132 @6624
//
// Phase 1 (proj): thread = 4 rows x 4 cols, k split across wave-halves
//   (A=16 -> W L1 traffic ~400KB/CU, at the FMA floor). Partials combined
//   through LDS. q and b-query stay in LDS; k/v/b to workspace.
// Grid barrier: device-scope atomic counter (memset to 0 each launch by a
//   captured hipMemsetAsync) + __threadfence both sides.
// Phase 3 (attn): R2's measured-good body; wave = head pair; per-wave
//   vt[128][17] + ew; masked-exp no-max softmax; folded prob-sum butterfly.
// Out-proj: same split-k template with Wo, input tile from LDS.
// ---------------------------------------------------------------------------
__global__ __launch_bounds__(256, 2) void fused_kernel(
    const float* __restrict__ query, const float* __restrict__ key,
    const float* __restrict__ value, const float* __restrict__ attn_bias,
    const float* __restrict__ Wq, const float* __restrict__ bq,
    const float* __restrict__ Wk, const float* __restrict__ bk,
    const float* __restrict__ Wv, const float* __restrict__ bv,
    const float* __restrict__ Wo, const float* __restrict__ bo,
    const float* __restrict__ Wfe, const float* __restrict__ bfe,
    float* __restrict__ kw, float* __restrict__ vw, float* __restrict__ bw,
    unsigned* cnt, float* __restrict__ out)
{
    extern __shared__ __align__(16) float smem[];
    float* qs   = smem;            // [16][128]
    float* bs   = smem + 2048;     // [16][128]
    float* ew   = smem + 4096;     // [4][104]
    float* at   = smem + 4512;     // [16][132]
    float* xs   = smem + 6624;     // [3][16][128]
    float* ab   = smem + 12768;    // [128]
    float* part = smem + 12896;    // [2][16][132]
    float* vt   = smem + 6624;     // [4][128][17]   (phase 3 alias)
    float* pO   = smem + 6624;     // [2][16][132]   (out alias)

    const int tid = threadIdx.x;
    const int i0  = blockIdx.x * 16;
    const int c4  = tid & 31;

    // ===== stage X tiles + attn_bias =====
    {
        const float* srcs[3] = {query, key, value};
        #pragma unroll
        for (int u = 0; u < 6; ++u) {
            const int f = tid + 256 * u;          // 1536 float4s
            const int m = f >> 9, r = (f >> 5) & 15, q = f & 31;
            *(float4*)&xs[m * 2048 + r * 128 + q * 4] =
                ((const float4*)(srcs[m] + (size_t)(i0 + r) * E))[q];
        }
        if (tid < 128) ab[tid] = attn_bias[(size_t)i0 * H + tid];
    }
    __syncthreads();

    // ===== feature projection (K = 8): rows rs, rs+8 =====
    {
        const int rs = tid >> 5;                  // 0..7
        float4 a0 = ((const float4*)bfe)[c4];
        float4 a1 = a0;
        #pragma unroll
        for (int kk = 0; kk < 8; ++kk) {
            const float4 wf = ((const float4*)(Wfe + (size_t)kk * E))[c4];
            const float f0 = ab[rs * 8 + kk];
            const float f1 = ab[(rs + 8) * 8 + kk];
            a0.x = fmaf(f0, wf.x, a0.x); a0.y = fmaf(f0, wf.y, a0.y);
            a0.z = fmaf(f0, wf.z, a0.z); a0.w = fmaf(f0, wf.w, a0.w);
            a1.x = fmaf(f1, wf.x, a1.x); a1.y = fmaf(f1, wf.y, a1.y);
            a1.z = fmaf(f1, wf.z, a1.z); a1.w = fmaf(f1, wf.w, a1.w);
        }
        *(float4*)&bs[rs * 128 + c4 * 4]       = a0;
        *(float4*)&bs[(rs + 8) * 128 + c4 * 4] = a1;
        *(float4*)(bw + (size_t)(i0 + rs) * E + c4 * 4)     = a0;
        *(float4*)(bw + (size_t)(i0 + rs + 8) * E + c4 * 4) = a1;
    }

    // ===== q/k/v projections: split-k halves, 4 rows x 4 cols / thread =====
    const int wh = tid >> 7;          // k-half (0/1)
    const int rs = (tid >> 5) & 3;    // row group: rows rs, rs+4, rs+8, rs+12
    const int kb = wh * 64;
    const float* Wms[3] = {Wq, Wk, Wv};
    #pragma unroll
    for (int m = 0; m < 3; ++m) {
        float4 a0 = make_float4(0.f, 0.f, 0.f, 0.f);
        float4 a1 = a0, a2 = a0, a3 = a0;
        #pragma unroll 4
        for (int kk = 0; kk < 64; kk += 4) {
            const int k = kb + kk;
            const float4 w0 = ((const float4*)(Wms[m] + (size_t)(k + 0) * E))[c4];
            const float4 w1 = ((const float4*)(Wms[m] + (size_t)(k + 1) * E))[c4];
            const float4 w2 = ((const float4*)(Wms[m] + (size_t)(k + 2) * E))[c4];
            const float4 w3 = ((const float4*)(Wms[m] + (size_t)(k + 3) * E))[c4];
            const float4 x0 = *(const float4*)&xs[m * 2048 + (rs +  0) * 128 + k];
            const float4 x1 = *(const float4*)&xs[m * 2048 + (rs +  4) * 128 + k];
            const float4 x2 = *(const float4*)&xs[m * 2048 + (rs +  8) * 128 + k];
            const float4 x3 = *(const float4*)&xs[m * 2048 + (rs + 12) * 128 + k];
            fma4x4(x0, w0, w1, w2, w3, a0);
            fma4x4(x1, w0, w1, w2, w3, a1);
            fma4x4(x2, w0, w1, w2, w3, a2);
            fma4x4(x3, w0, w1, w2, w3, a3);
        }
        *(float4*)&part[wh * 2112 + (rs +  0) * 132 + c4 * 4] = a0;
        *(float4*)&part[wh * 2112 + (rs +  4) * 132 + c4 * 4] = a1;
        *(float4*)&part[wh * 2112 + (rs +  8) * 132 + c4 * 4] = a2;
        *(float4*)&part[wh * 2112 + (rs + 12) * 132 + c4 * 4] = a3;
        __syncthreads();
        const float* bias = (m == 0) ? bq : (m == 1) ? bk : bv;
        #pragma unroll
        for (int u = 0; u < 2; ++u) {
            const int o = tid + 256 * u;          // 512 float4 outputs
            const int row = o >> 5, q = o & 31;
            const float4 p0 = *(const float4*)&part[row * 132 + q * 4];
            const float4 p1 = *(const float4*)&part[2112 + row * 132 + q * 4];
            const float4 bb = ((const float4*)bias)[q];
            const float4 r4 = make_float4(p0.x + p1.x + bb.x, p0.y + p1.y + bb.y,
                                          p0.z + p1.z + bb.z, p0.w + p1.w + bb.w);
            if (m == 0)      *(float4*)&qs[row * 128 + q * 4] = r4;
            else if (m == 1) *(float4*)(kw + (size_t)(i0 + row) * E + q * 4) = r4;
            else             *(float4*)(vw + (size_t)(i0 + row) * E + q * 4) = r4;
        }
        __syncthreads();
    }

    // ===== grid barrier (device-scope; counter memset to 0 per launch) =====
    __threadfence();
    __syncthreads();
    if (tid == 0) {
        atomicAdd(cnt, 1u);
        while (atomicAdd(cnt, 0u) < (unsigned)NBLK)
            __builtin_amdgcn_s_sleep(2);
    }
    __syncthreads();
    __threadfence();

    // ===== phase 3: banded attention (wave = head pair) =====
    const int lane = tid & 63;
    const int wv_  = tid >> 6;                    // 0..3
    const int base = i0 - SPAN;

    float* vtw = vt + wv_ * 2176;                 // [128][17]
    float* eww = ew + wv_ * 104;

    const int p0 = base + lane;
    const int p1 = p0 + 64;
    const bool in0 = (p0 >= 0);                   // p0 <= i0+13 < N always
    const bool in1 = (p1 < N);                    // p1 >= 14 always
    const int cc0 = p0 < 0 ? 0 : p0;
    const int cc1 = p1 > N - 1 ? N - 1 : p1;

    const float scale = 1.0f / 64.0f;             // 1/sqrt(4096)
    const int d = lane & 15;
    const int g = lane >> 4;

    #pragma unroll
    for (int pass = 0; pass < 2; ++pass) {
        const int h = wv_ * 2 + pass;

        // stage V window for this head (per-wave buffer, pad 17)
        {
            const int x4 = lane & 3, rr = lane >> 2;
            #pragma unroll
            for (int rep = 0; rep < 8; ++rep) {
                const int r = rep * 16 + rr;
                int j = base + r;
                j = j < 0 ? 0 : (j > N - 1 ? N - 1 : j);
                const float4 t = *(const float4*)(vw + (size_t)j * E + h * D + x4 * 4);
                vtw[r * 17 + x4 * 4 + 0] = t.x; vtw[r * 17 + x4 * 4 + 1] = t.y;
                vtw[r * 17 + x4 * 4 + 2] = t.z; vtw[r * 17 + x4 * 4 + 3] = t.w;
            }
        }
        // K/B rows for this lane's two positions -> registers
        float k0[16], k1[16], g0[16], g1[16];
        {
            const float4* kp0 = (const float4*)(kw + (size_t)cc0 * E + h * D);
            const float4* kp1 = (const float4*)(kw + (size_t)cc1 * E + h * D);
            const float4* gp0 = (const float4*)(bw + (size_t)cc0 * E + h * D);
            const float4* gp1 = (const float4*)(bw + (size_t)cc1 * E + h * D);
            #pragma unroll
            for (int x = 0; x < 4; ++x) {
                float4 t;
                t = kp0[x]; k0[4*x]=t.x; k0[4*x+1]=t.y; k0[4*x+2]=t.z; k0[4*x+3]=t.w;
                t = kp1[x]; k1[4*x]=t.x; k1[4*x+1]=t.y; k1[4*x+2]=t.z; k1[4*x+3]=t.w;
                t = gp0[x]; g0[4*x]=t.x; g0[4*x+1]=t.y; g0[4*x+2]=t.z; g0[4*x+3]=t.w;
                t = gp1[x]; g1[4*x]=t.x; g1[4*x+1]=t.y; g1[4*x+2]=t.z; g1[4*x+3]=t.w;
            }
        }

        for (int r = 0; r < 16; ++r) {
            float sq0 = 0.f, sq1 = 0.f, sb0 = 0.f, sb1 = 0.f;
            #pragma unroll
            for (int x = 0; x < 16; ++x) {
                const float qv = qs[r * 128 + h * D + x];   // LDS broadcast
                const float bv = bs[r * 128 + h * D + x];
                sq0 = fmaf(qv, k0[x], sq0);
                sq1 = fmaf(qv, k1[x], sq1);
                sb0 = fmaf(bv, g0[x], sb0);
                sb1 = fmaf(bv, g1[x], sb1);
            }
            // w0 = lane-r in [0,100]; w1 = 64+lane-r <= 100
            const bool ok0 = in0 && (lane >= r);
            const bool ok1 = in1 && (lane <= r + 36);
            // masked exp, no max-subtraction (validated R3-R9, absmax ~1e-3)
            const float e0 = ok0 ? __expf(sq0 * scale + sb0) : 0.f;
            const float e1 = ok1 ? __expf(sq1 * scale + sb1) : 0.f;

            if (lane >= r)      eww[lane - r]      = e0;
            if (lane <= r + 36) eww[64 + lane - r] = e1;
            // same-wave ds write->read is ordered (R3-proven) — no barrier

            float acc = 0.f, as = 0.f;
            #pragma unroll
            for (int it = 0; it < 25; ++it) {
                const int w = g + 4 * it;                   // <= 99
                const float p = eww[w];
                acc = fmaf(p, vtw[(w + r) * 17 + d], acc);
                as += p;
            }
            if (g == 0) {
                const float p = eww[100];
                acc = fmaf(p, vtw[(100 + r) * 17 + d], acc);
                as += p;
            }
            acc += __shfl_xor(acc, 16); as += __shfl_xor(as, 16);
            acc += __shfl_xor(acc, 32); as += __shfl_xor(as, 32);
            if (lane < D) at[r * 132 + h * D + lane] = acc / as;
        }
    }
    __syncthreads();

    // ===== out projection: same split-k template, input tile = at =====
    {
        float4 a0 = make_float4(0.f, 0.f, 0.f, 0.f);
        float4 a1 = a0, a2 = a0, a3 = a0;
        #pragma unroll 4
        for (int kk = 0; kk < 64; kk += 4) {
            const int k = kb + kk;
            const float4 w0 = ((const float4*)(Wo + (size_t)(k + 0) * E))[c4];
            const float4 w1 = ((const float4*)(Wo + (size_t)(k + 1) * E))[c4];
            const float4 w2 = ((const float4*)(Wo + (size_t)(k + 2) * E))[c4];
            const float4 w3 = ((const float4*)(Wo + (size_t)(k + 3) * E))[c4];
            const float4 x0 = *(const float4*)&at[(rs +  0) * 132 + k];
            const float4 x1 = *(const float4*)&at[(rs +  4) * 132 + k];
            const float4 x2 = *(const float4*)&at[(rs +  8) * 132 + k];
            const float4 x3 = *(const float4*)&at[(rs + 12) * 132 + k];
            fma4x4(x0, w0, w1, w2, w3, a0);
            fma4x4(x1, w0, w1, w2, w3, a1);
            fma4x4(x2, w0, w1, w2, w3, a2);
            fma4x4(x3, w0, w1, w2, w3, a3);
        }
        *(float4*)&pO[wh * 2112 + (rs +  0) * 132 + c4 * 4] = a0;
        *(float4*)&pO[wh * 2112 + (rs +  4) * 132 + c4 * 4] = a1;
        *(float4*)&pO[wh * 2112 + (rs +  8) * 132 + c4 * 4] = a2;
        *(float4*)&pO[wh * 2112 + (rs + 12) * 132 + c4 * 4] = a3;
        __syncthreads();
        #pragma unroll
        for (int u = 0; u < 2; ++u) {
            const int o = tid + 256 * u;
            const int row = o >> 5, q = o & 31;
            const float4 p0 = *(const float4*)&pO[row * 132 + q * 4];
            const float4 p1 = *(const float4*)&pO[2112 + row * 132 + q * 4];
            const float4 bb = ((const float4*)bo)[q];
            *(float4*)(out + (size_t)(i0 + row) * E + q * 4) =
                make_float4(p0.x + p1.x + bb.x, p0.y + p1.y + bb.y,
                            p0.z + p1.z + bb.z, p0.w + p1.w + bb.w);
        }
    }
}

// ---------------------------------------------------------------------------
extern "C" void kernel_launch(void* const* d_in, const int* in_sizes, int n_in,
                              void* d_out, int out_size, void* d_ws, size_t ws_size,
                              hipStream_t stream) {
    const float* query     = (const float*)d_in[0];
    const float* key       = (const float*)d_in[1];
    const float* value     = (const float*)d_in[2];
    const float* attn_bias = (const float*)d_in[3];
    const float* Wq  = (const float*)d_in[4];
    const float* bq  = (const float*)d_in[5];
    const float* Wk  = (const float*)d_in[6];
    const float* bk  = (const float*)d_in[7];
    const float* Wv  = (const float*)d_in[8];
    const float* bv  = (const float*)d_in[9];
    const float* Wo  = (const float*)d_in[10];
    const float* bo  = (const float*)d_in[11];
    const float* Wfe = (const float*)d_in[12];
    const float* bfe = (const float*)d_in[13];

    float* ws = (float*)d_ws;
    const int NE = N * E;
    float* kw = ws;
    float* vw = ws + 1 * NE;
    float* bw = ws + 2 * NE;
    unsigned* cnt = (unsigned*)(ws + 3 * NE);

    // re-arm the barrier counter on every launch (captured into the graph)
    hipMemsetAsync(cnt, 0, sizeof(unsigned), stream);

    fused_kernel<<<NBLK, 256, 17120 * sizeof(float), stream>>>(
        query, key, value, attn_bias, Wq, bq, Wk, bk, Wv, bv, Wo, bo,
        Wfe, bfe, kw, vw, bw, cnt, (float*)d_out);
}

// Round 13
// 47.626 us; speedup vs baseline: 2.3073x; 2.3073x over previous
//
#include <hip/hip_runtime.h>
#include <math.h>

// Problem constants (fixed by the reference setup)
constexpr int N = 4096;
constexpr int E = 128;
constexpr int H = 8;
constexpr int D = 16;      // E / H
constexpr int SPAN = 50;

// ---------------------------------------------------------------------------
// Shared GEMM building blocks (R4 versions, verbatim — the 51.5us config).
// ---------------------------------------------------------------------------
__device__ __forceinline__ void gemm_fma4(const float4 x, const float4 w0,
                                          const float4 w1, const float4 w2,
                                          const float4 w3, float4& a)
{
    a.x = fmaf(x.x, w0.x, a.x); a.y = fmaf(x.x, w0.y, a.y);
    a.z = fmaf(x.x, w0.z, a.z); a.w = fmaf(x.x, w0.w, a.w);
    a.x = fmaf(x.y, w1.x, a.x); a.y = fmaf(x.y, w1.y, a.y);
    a.z = fmaf(x.y, w1.z, a.z); a.w = fmaf(x.y, w1.w, a.w);
    a.x = fmaf(x.z, w2.x, a.x); a.y = fmaf(x.z, w2.y, a.y);
    a.z = fmaf(x.z, w2.z, a.z); a.w = fmaf(x.z, w2.w, a.w);
    a.x = fmaf(x.w, w3.x, a.x); a.y = fmaf(x.w, w3.y, a.y);
    a.z = fmaf(x.w, w3.z, a.z); a.w = fmaf(x.w, w3.w, a.w);
}

__device__ __forceinline__ void gemm_half_8x128(
    const float* __restrict__ xs, const float* __restrict__ Wm,
    int h, int c4, int r0, float4 acc[4])
{
    const int kbase = h * 64;
    #pragma unroll 2
    for (int kk = 0; kk < 64; kk += 4) {
        const int k = kbase + kk;
        const float4 w0 = ((const float4*)(Wm + (size_t)(k + 0) * E))[c4];
        const float4 w1 = ((const float4*)(Wm + (size_t)(k + 1) * E))[c4];
        const float4 w2 = ((const float4*)(Wm + (size_t)(k + 2) * E))[c4];
        const float4 w3 = ((const float4*)(Wm + (size_t)(k + 3) * E))[c4];
        #pragma unroll
        for (int i = 0; i < 4; ++i) {
            const float4 x = *(const float4*)&xs[(r0 + i) * E + k];
            gemm_fma4(x, w0, w1, w2, w3, acc[i]);
        }
    }
}

__device__ __forceinline__ void combine_store(
    float* __restrict__ part, const float4 acc[4], int h, int c4, int r0,
    int tid, const float* __restrict__ bias, float* __restrict__ outp, int row0)
{
    #pragma unroll
    for (int i = 0; i < 4; ++i)
        *(float4*)&part[(size_t)(h * 8 + r0 + i) * 132 + c4 * 4] = acc[i];
    __syncthreads();
    #pragma unroll
    for (int rr = 0; rr < 2; ++rr) {
        const int idx = tid + 128 * rr;
        const int row = idx >> 5, q = idx & 31;
        const float4 p0 = *(const float4*)&part[(size_t)row * 132 + q * 4];
        const float4 p1 = *(const float4*)&part[(size_t)(8 + row) * 132 + q * 4];
        const float4 bb = ((const float4*)bias)[q];
        const float4 o  = make_float4(p0.x + p1.x + bb.x, p0.y + p1.y + bb.y,
                                      p0.z + p1.z + bb.z, p0.w + p1.w + bb.w);
        *(float4*)&outp[(size_t)(row0 + row) * E + q * 4] = o;
    }
    __syncthreads();
}

// ---------------------------------------------------------------------------
// Kernel 1: fused projections (R4 version, verbatim).
// ---------------------------------------------------------------------------
__global__ __launch_bounds__(128) void proj_kernel(
    const float* __restrict__ query, const float* __restrict__ key,
    const float* __restrict__ value, const float* __restrict__ attn_bias,
    const float* __restrict__ Wq, const float* __restrict__ bq,
    const float* __restrict__ Wk, const float* __restrict__ bk,
    const float* __restrict__ Wv, const float* __restrict__ bv,
    const float* __restrict__ Wfe, const float* __restrict__ bfe,
    float* __restrict__ qo, float* __restrict__ ko,
    float* __restrict__ vo, float* __restrict__ bo_)
{
    __shared__ float xs[3][8][E];
    __shared__ float ab[8][8];
    __shared__ float part[2 * 8 * 132];

    const int tid  = threadIdx.x;
    const int c4   = tid & 31;
    const int r0   = ((tid >> 5) & 1) * 4;
    const int h    = tid >> 6;
    const int row0 = blockIdx.x * 8;

    #pragma unroll
    for (int m = 0; m < 3; ++m) {
        const float* s = (m == 0) ? query : (m == 1) ? key : value;
        #pragma unroll
        for (int rr = 0; rr < 2; ++rr) {
            const int idx = tid + 128 * rr;
            const int row = idx >> 5, q = idx & 31;
            *(float4*)&xs[m][row][q * 4] =
                ((const float4*)(s + (size_t)(row0 + row) * E))[q];
        }
    }
    if (tid < 64) ab[tid >> 3][tid & 7] = attn_bias[(size_t)row0 * H + tid];
    __syncthreads();

    float4 acc[4];

    #pragma unroll
    for (int i = 0; i < 4; ++i) acc[i] = make_float4(0.f, 0.f, 0.f, 0.f);
    gemm_half_8x128(&xs[0][0][0], Wq, h, c4, r0, acc);
    combine_store(part, acc, h, c4, r0, tid, bq, qo, row0);

    #pragma unroll
    for (int i = 0; i < 4; ++i) acc[i] = make_float4(0.f, 0.f, 0.f, 0.f);
    gemm_half_8x128(&xs[1][0][0], Wk, h, c4, r0, acc);
    combine_store(part, acc, h, c4, r0, tid, bk, ko, row0);

    #pragma unroll
    for (int i = 0; i < 4; ++i) acc[i] = make_float4(0.f, 0.f, 0.f, 0.f);
    gemm_half_8x128(&xs[2][0][0], Wv, h, c4, r0, acc);
    combine_store(part, acc, h, c4, r0, tid, bv, vo, row0);

    #pragma unroll
    for (int i = 0; i < 4; ++i) acc[i] = make_float4(0.f, 0.f, 0.f, 0.f);
    {
        const float4 w0 = ((const float4*)(Wfe + (size_t)(h * 4 + 0) * E))[c4];
        const float4 w1 = ((const float4*)(Wfe + (size_t)(h * 4 + 1) * E))[c4];
        const float4 w2 = ((const float4*)(Wfe + (size_t)(h * 4 + 2) * E))[c4];
        const float4 w3 = ((const float4*)(Wfe + (size_t)(h * 4 + 3) * E))[c4];
        #pragma unroll
        for (int i = 0; i < 4; ++i) {
            const float4 x = *(const float4*)&ab[r0 + i][h * 4];
            gemm_fma4(x, w0, w1, w2, w3, acc[i]);
        }
    }
    combine_store(part, acc, h, c4, r0, tid, bfe, bo_, row0);
}

// ---------------------------------------------------------------------------
// Kernel 2: fused banded attention + output projection.
// 512 blocks x 512 threads (8 waves); block = 8-row tile; wave = head.
// Attention phase: ZERO barriers (per-wave vt[128][17] + ew[104]; same-wave
// LDS ordering). One barrier, then split-K out-proj with coalesced Wo.
// FIX vs R11: in0/c0 now also bounded ABOVE (p0 can reach i0+13 up to 4101
// with 8-row tiles — the 16-row invariant "p0 < N always" does not port).
// ---------------------------------------------------------------------------
__global__ __launch_bounds__(512, 4) void attn_out_kernel(
    const float* __restrict__ qw, const float* __restrict__ kw,
    const float* __restrict__ vw, const float* __restrict__ bw,
    const float* __restrict__ Wo, const float* __restrict__ bop,
    float* __restrict__ out)
{
    __shared__ __align__(16) float vt[8][2176];   // per-wave V [128][17]
    __shared__ float ewb[8][104];                 // per-wave exp weights
    __shared__ float at[8 * 132];                 // attn tile [8][132]

    const int tid  = threadIdx.x;
    const int lane = tid & 63;
    const int h    = __builtin_amdgcn_readfirstlane(tid >> 6);  // head
    const int i0   = blockIdx.x * 8;
    const int base = i0 - SPAN;

    float* vtw = &vt[h][0];
    float* eww = &ewb[h][0];

    // ---- stage V window for this head (per-wave, no barrier needed) ----
    {
        const int x4 = lane & 3, rr = lane >> 2;
        #pragma unroll
        for (int rep = 0; rep < 8; ++rep) {
            const int r = rep * 16 + rr;
            int j = base + r;
            j = j < 0 ? 0 : (j > N - 1 ? N - 1 : j);
            const float4 t = *(const float4*)(vw + (size_t)j * E + h * D + x4 * 4);
            vtw[r * 17 + x4 * 4 + 0] = t.x; vtw[r * 17 + x4 * 4 + 1] = t.y;
            vtw[r * 17 + x4 * 4 + 2] = t.z; vtw[r * 17 + x4 * 4 + 3] = t.w;
        }
    }

    // ---- K/B(feature) rows for this lane's two positions -> registers ----
    const int p0 = base + lane;
    const int p1 = p0 + 64;
    const bool in0 = (p0 >= 0) && (p0 < N);   // FIX: both bounds
    const bool in1 = (p1 < N);                // p1 >= 14 always
    const int c0 = p0 < 0 ? 0 : (p0 > N - 1 ? N - 1 : p0);   // FIX: clamp high
    const int c1 = p1 > N - 1 ? N - 1 : p1;

    float k0[16], k1[16], g0[16], g1[16];
    {
        const float4* kp0 = (const float4*)(kw + (size_t)c0 * E + h * D);
        const float4* kp1 = (const float4*)(kw + (size_t)c1 * E + h * D);
        const float4* gp0 = (const float4*)(bw + (size_t)c0 * E + h * D);
        const float4* gp1 = (const float4*)(bw + (size_t)c1 * E + h * D);
        #pragma unroll
        for (int x = 0; x < 4; ++x) {
            float4 t;
            t = kp0[x]; k0[4*x]=t.x; k0[4*x+1]=t.y; k0[4*x+2]=t.z; k0[4*x+3]=t.w;
            t = kp1[x]; k1[4*x]=t.x; k1[4*x+1]=t.y; k1[4*x+2]=t.z; k1[4*x+3]=t.w;
            t = gp0[x]; g0[4*x]=t.x; g0[4*x+1]=t.y; g0[4*x+2]=t.z; g0[4*x+3]=t.w;
            t = gp1[x]; g1[4*x]=t.x; g1[4*x+1]=t.y; g1[4*x+2]=t.z; g1[4*x+3]=t.w;
        }
    }

    const float scale = 1.0f / 64.0f;        // 1/sqrt(4096)
    const int d = lane & 15;
    const int g = lane >> 4;

    for (int r = 0; r < 8; ++r) {
        // Q and B(query) rows: wave-uniform addresses -> scalar loads
        const float* qp = qw + (size_t)(i0 + r) * E + h * D;
        const float* bp = bw + (size_t)(i0 + r) * E + h * D;

        float sq0 = 0.f, sq1 = 0.f, sb0 = 0.f, sb1 = 0.f;
        #pragma unroll
        for (int x = 0; x < 16; ++x) {
            const float qv = qp[x];
            const float bv = bp[x];
            sq0 = fmaf(qv, k0[x], sq0);
            sq1 = fmaf(qv, k1[x], sq1);
            sb0 = fmaf(bv, g0[x], sb0);
            sb1 = fmaf(bv, g1[x], sb1);
        }
        // w0 = lane-r in [0,63-r]; w1 = 64+lane-r <= 100
        const bool ok0 = in0 && (lane >= r);
        const bool ok1 = in1 && (lane <= r + 36);
        // masked exp, no max-subtraction (validated R3-R11, absmax ~4e-3)
        const float e0 = ok0 ? __expf(sq0 * scale + sb0) : 0.f;
        const float e1 = ok1 ? __expf(sq1 * scale + sb1) : 0.f;

        if (lane >= r)      eww[lane - r]      = e0;
        if (lane <= r + 36) eww[64 + lane - r] = e1;
        // same-wave ds write->read is ordered — no barrier

        // PV with prob-sum folded into the butterfly
        float acc = 0.f, as = 0.f;
        #pragma unroll
        for (int it = 0; it < 25; ++it) {
            const int w = g + 4 * it;        // <= 99
            const float p = eww[w];
            acc = fmaf(p, vtw[(w + r) * 17 + d], acc);
            as += p;
        }
        if (g == 0) {
            const float p = eww[100];
            acc = fmaf(p, vtw[(100 + r) * 17 + d], acc);
            as += p;
        }
        acc += __shfl_xor(acc, 16); as += __shfl_xor(as, 16);
        acc += __shfl_xor(acc, 32); as += __shfl_xor(as, 32);
        if (lane < D) at[r * 132 + h * D + lane] = acc / as;
    }

    __syncthreads();   // at complete; vt dead -> reuse as split-K partials

    // ---- out-projection: split-K halves, Wo coalesced from global ----
    {
        float* part = &vt[0][0];             // [2][8][132]
        const int wh  = tid >> 8;            // k-half
        const int idx = tid & 255;
        const int c4  = idx & 31;
        const int row = idx >> 5;            // 0..7
        const int kb  = wh * 64;

        float4 acc = make_float4(0.f, 0.f, 0.f, 0.f);
        #pragma unroll 2
        for (int kk = 0; kk < 64; kk += 4) {
            const int k = kb + kk;
            const float4 w0 = ((const float4*)(Wo + (size_t)(k + 0) * E))[c4];
            const float4 w1 = ((const float4*)(Wo + (size_t)(k + 1) * E))[c4];
            const float4 w2 = ((const float4*)(Wo + (size_t)(k + 2) * E))[c4];
            const float4 w3 = ((const float4*)(Wo + (size_t)(k + 3) * E))[c4];
            const float4 x  = *(const float4*)&at[row * 132 + k];
            gemm_fma4(x, w0, w1, w2, w3, acc);
        }
        *(float4*)&part[(size_t)(wh * 8 + row) * 132 + c4 * 4] = acc;
        __syncthreads();

        if (tid < 256) {
            const int orow = tid >> 5, q = tid & 31;
            const float4 p0 = *(const float4*)&part[(size_t)orow * 132 + q * 4];
            const float4 p1 = *(const float4*)&part[(size_t)(8 + orow) * 132 + q * 4];
            const float4 bb = ((const float4*)bop)[q];
            *(float4*)(out + (size_t)(i0 + orow) * E + q * 4) =
                make_float4(p0.x + p1.x + bb.x, p0.y + p1.y + bb.y,
                            p0.z + p1.z + bb.z, p0.w + p1.w + bb.w);
        }
    }
}

// ---------------------------------------------------------------------------
extern "C" void kernel_launch(void* const* d_in, const int* in_sizes, int n_in,
                              void* d_out, int out_size, void* d_ws, size_t ws_size,
                              hipStream_t stream) {
    const float* query     = (const float*)d_in[0];
    const float* key       = (const float*)d_in[1];
    const float* value     = (const float*)d_in[2];
    const float* attn_bias = (const float*)d_in[3];
    const float* Wq  = (const float*)d_in[4];
    const float* bq  = (const float*)d_in[5];
    const float* Wk  = (const float*)d_in[6];
    const float* bk  = (const float*)d_in[7];
    const float* Wv  = (const float*)d_in[8];
    const float* bv  = (const float*)d_in[9];
    const float* Wo  = (const float*)d_in[10];
    const float* bo  = (const float*)d_in[11];
    const float* Wfe = (const float*)d_in[12];
    const float* bfe = (const float*)d_in[13];

    float* ws = (float*)d_ws;
    const int NE = N * E;
    float* qw = ws;
    float* kw = ws + 1 * NE;
    float* vw = ws + 2 * NE;
    float* bw = ws + 3 * NE;

    proj_kernel<<<N / 8, 128, 0, stream>>>(query, key, value, attn_bias,
                                           Wq, bq, Wk, bk, Wv, bv, Wfe, bfe,
                                           qw, kw, vw, bw);
    attn_out_kernel<<<N / 8, 512, 0, stream>>>(qw, kw, vw, bw, Wo, bo,
                                               (float*)d_out);
}

// Round 14
// 43.903 us; speedup vs baseline: 2.5029x; 1.0848x over previous
//
#include <hip/hip_runtime.h>
#include <math.h>

// Problem constants (fixed by the reference setup)
constexpr int N = 4096;
constexpr int E = 128;
constexpr int H = 8;
constexpr int D = 16;      // E / H
constexpr int SPAN = 50;

// ---------------------------------------------------------------------------
// Shared GEMM building blocks (R4 versions, verbatim).
// ---------------------------------------------------------------------------
__device__ __forceinline__ void gemm_fma4(const float4 x, const float4 w0,
                                          const float4 w1, const float4 w2,
                                          const float4 w3, float4& a)
{
    a.x = fmaf(x.x, w0.x, a.x); a.y = fmaf(x.x, w0.y, a.y);
    a.z = fmaf(x.x, w0.z, a.z); a.w = fmaf(x.x, w0.w, a.w);
    a.x = fmaf(x.y, w1.x, a.x); a.y = fmaf(x.y, w1.y, a.y);
    a.z = fmaf(x.y, w1.z, a.z); a.w = fmaf(x.y, w1.w, a.w);
    a.x = fmaf(x.z, w2.x, a.x); a.y = fmaf(x.z, w2.y, a.y);
    a.z = fmaf(x.z, w2.z, a.z); a.w = fmaf(x.z, w2.w, a.w);
    a.x = fmaf(x.w, w3.x, a.x); a.y = fmaf(x.w, w3.y, a.y);
    a.z = fmaf(x.w, w3.z, a.z); a.w = fmaf(x.w, w3.w, a.w);
}

__device__ __forceinline__ void gemm_half_8x128(
    const float* __restrict__ xs, const float* __restrict__ Wm,
    int h, int c4, int r0, float4 acc[4])
{
    const int kbase = h * 64;
    #pragma unroll 2
    for (int kk = 0; kk < 64; kk += 4) {
        const int k = kbase + kk;
        const float4 w0 = ((const float4*)(Wm + (size_t)(k + 0) * E))[c4];
        const float4 w1 = ((const float4*)(Wm + (size_t)(k + 1) * E))[c4];
        const float4 w2 = ((const float4*)(Wm + (size_t)(k + 2) * E))[c4];
        const float4 w3 = ((const float4*)(Wm + (size_t)(k + 3) * E))[c4];
        #pragma unroll
        for (int i = 0; i < 4; ++i) {
            const float4 x = *(const float4*)&xs[(r0 + i) * E + k];
            gemm_fma4(x, w0, w1, w2, w3, acc[i]);
        }
    }
}

__device__ __forceinline__ void combine_store(
    float* __restrict__ part, const float4 acc[4], int h, int c4, int r0,
    int tid, const float* __restrict__ bias, float* __restrict__ outp, int row0)
{
    #pragma unroll
    for (int i = 0; i < 4; ++i)
        *(float4*)&part[(size_t)(h * 8 + r0 + i) * 132 + c4 * 4] = acc[i];
    __syncthreads();
    #pragma unroll
    for (int rr = 0; rr < 2; ++rr) {
        const int idx = tid + 128 * rr;
        const int row = idx >> 5, q = idx & 31;
        const float4 p0 = *(const float4*)&part[(size_t)row * 132 + q * 4];
        const float4 p1 = *(const float4*)&part[(size_t)(8 + row) * 132 + q * 4];
        const float4 bb = ((const float4*)bias)[q];
        const float4 o  = make_float4(p0.x + p1.x + bb.x, p0.y + p1.y + bb.y,
                                      p0.z + p1.z + bb.z, p0.w + p1.w + bb.w);
        *(float4*)&outp[(size_t)(row0 + row) * E + q * 4] = o;
    }
    __syncthreads();
}

// ---------------------------------------------------------------------------
// Kernel 1: projections — R4's split-K block, but ONE MATRIX PER BLOCK.
// Grid = 3 x 512 = 1536 blocks x 128 threads (2 waves) = 3072 waves
// = 3 waves/SIMD (vs R4's 1), same per-wave W-load shape (c4 = tid&31:
// 32 distinct quads/wave, A=16 acc elems/thread).
// mat==0 blocks also compute the (K=8) feature projection for their rows.
// ---------------------------------------------------------------------------
__global__ __launch_bounds__(128) void proj_kernel(
    const float* __restrict__ query, const float* __restrict__ key,
    const float* __restrict__ value, const float* __restrict__ attn_bias,
    const float* __restrict__ Wq, const float* __restrict__ bq,
    const float* __restrict__ Wk, const float* __restrict__ bk,
    const float* __restrict__ Wv, const float* __restrict__ bv,
    const float* __restrict__ Wfe, const float* __restrict__ bfe,
    float* __restrict__ qo, float* __restrict__ ko,
    float* __restrict__ vo, float* __restrict__ bo_)
{
    __shared__ float xs[8][E];
    __shared__ float ab[8][8];
    __shared__ float part[2 * 8 * 132];

    const int tid  = threadIdx.x;
    const int c4   = tid & 31;
    const int r0   = ((tid >> 5) & 1) * 4;
    const int h    = tid >> 6;               // k-half
    const int bid  = blockIdx.x;
    const int mat  = bid >> 9;               // 0=q, 1=k, 2=v
    const int row0 = (bid & 511) * 8;

    const float* src  = mat == 0 ? query : (mat == 1 ? key : value);
    const float* Wm   = mat == 0 ? Wq : (mat == 1 ? Wk : Wv);
    const float* bias = mat == 0 ? bq : (mat == 1 ? bk : bv);
    float*       dst  = mat == 0 ? qo : (mat == 1 ? ko : vo);

    // stage the 8x128 X tile (2 coalesced float4 per thread)
    #pragma unroll
    for (int rr = 0; rr < 2; ++rr) {
        const int idx = tid + 128 * rr;
        const int row = idx >> 5, q = idx & 31;
        *(float4*)&xs[row][q * 4] =
            ((const float4*)(src + (size_t)(row0 + row) * E))[q];
    }
    if (mat == 0 && tid < 64) ab[tid >> 3][tid & 7] = attn_bias[(size_t)row0 * H + tid];
    __syncthreads();

    float4 acc[4];
    #pragma unroll
    for (int i = 0; i < 4; ++i) acc[i] = make_float4(0.f, 0.f, 0.f, 0.f);
    gemm_half_8x128(&xs[0][0], Wm, h, c4, r0, acc);
    combine_store(part, acc, h, c4, r0, tid, bias, dst, row0);

    if (mat == 0) {
        // feature projection: b = attn_bias @ Wfe + bfe (K=8, split 4/4)
        #pragma unroll
        for (int i = 0; i < 4; ++i) acc[i] = make_float4(0.f, 0.f, 0.f, 0.f);
        const float4 w0 = ((const float4*)(Wfe + (size_t)(h * 4 + 0) * E))[c4];
        const float4 w1 = ((const float4*)(Wfe + (size_t)(h * 4 + 1) * E))[c4];
        const float4 w2 = ((const float4*)(Wfe + (size_t)(h * 4 + 2) * E))[c4];
        const float4 w3 = ((const float4*)(Wfe + (size_t)(h * 4 + 3) * E))[c4];
        #pragma unroll
        for (int i = 0; i < 4; ++i) {
            const float4 x = *(const float4*)&ab[r0 + i][h * 4];
            gemm_fma4(x, w0, w1, w2, w3, acc[i]);
        }
        combine_store(part, acc, h, c4, r0, tid, bfe, bo_, row0);
    }
}

// ---------------------------------------------------------------------------
// Kernel 2: fused banded attention + output projection (R13 version, verbatim
// — the 47.6us config).
// ---------------------------------------------------------------------------
__global__ __launch_bounds__(512, 4) void attn_out_kernel(
    const float* __restrict__ qw, const float* __restrict__ kw,
    const float* __restrict__ vw, const float* __restrict__ bw,
    const float* __restrict__ Wo, const float* __restrict__ bop,
    float* __restrict__ out)
{
    __shared__ __align__(16) float vt[8][2176];   // per-wave V [128][17]
    __shared__ float ewb[8][104];                 // per-wave exp weights
    __shared__ float at[8 * 132];                 // attn tile [8][132]

    const int tid  = threadIdx.x;
    const int lane = tid & 63;
    const int h    = __builtin_amdgcn_readfirstlane(tid >> 6);  // head
    const int i0   = blockIdx.x * 8;
    const int base = i0 - SPAN;

    float* vtw = &vt[h][0];
    float* eww = &ewb[h][0];

    // ---- stage V window for this head (per-wave, no barrier needed) ----
    {
        const int x4 = lane & 3, rr = lane >> 2;
        #pragma unroll
        for (int rep = 0; rep < 8; ++rep) {
            const int r = rep * 16 + rr;
            int j = base + r;
            j = j < 0 ? 0 : (j > N - 1 ? N - 1 : j);
            const float4 t = *(const float4*)(vw + (size_t)j * E + h * D + x4 * 4);
            vtw[r * 17 + x4 * 4 + 0] = t.x; vtw[r * 17 + x4 * 4 + 1] = t.y;
            vtw[r * 17 + x4 * 4 + 2] = t.z; vtw[r * 17 + x4 * 4 + 3] = t.w;
        }
    }

    // ---- K/B(feature) rows for this lane's two positions -> registers ----
    const int p0 = base + lane;
    const int p1 = p0 + 64;
    const bool in0 = (p0 >= 0) && (p0 < N);
    const bool in1 = (p1 < N);                // p1 >= 14 always
    const int c0 = p0 < 0 ? 0 : (p0 > N - 1 ? N - 1 : p0);
    const int c1 = p1 > N - 1 ? N - 1 : p1;

    float k0[16], k1[16], g0[16], g1[16];
    {
        const float4* kp0 = (const float4*)(kw + (size_t)c0 * E + h * D);
        const float4* kp1 = (const float4*)(kw + (size_t)c1 * E + h * D);
        const float4* gp0 = (const float4*)(bw + (size_t)c0 * E + h * D);
        const float4* gp1 = (const float4*)(bw + (size_t)c1 * E + h * D);
        #pragma unroll
        for (int x = 0; x < 4; ++x) {
            float4 t;
            t = kp0[x]; k0[4*x]=t.x; k0[4*x+1]=t.y; k0[4*x+2]=t.z; k0[4*x+3]=t.w;
            t = kp1[x]; k1[4*x]=t.x; k1[4*x+1]=t.y; k1[4*x+2]=t.z; k1[4*x+3]=t.w;
            t = gp0[x]; g0[4*x]=t.x; g0[4*x+1]=t.y; g0[4*x+2]=t.z; g0[4*x+3]=t.w;
            t = gp1[x]; g1[4*x]=t.x; g1[4*x+1]=t.y; g1[4*x+2]=t.z; g1[4*x+3]=t.w;
        }
    }

    const float scale = 1.0f / 64.0f;        // 1/sqrt(4096)
    const int d = lane & 15;
    const int g = lane >> 4;

    for (int r = 0; r < 8; ++r) {
        // Q and B(query) rows: wave-uniform addresses -> scalar loads
        const float* qp = qw + (size_t)(i0 + r) * E + h * D;
        const float* bp = bw + (size_t)(i0 + r) * E + h * D;

        float sq0 = 0.f, sq1 = 0.f, sb0 = 0.f, sb1 = 0.f;
        #pragma unroll
        for (int x = 0; x < 16; ++x) {
            const float qv = qp[x];
            const float bv = bp[x];
            sq0 = fmaf(qv, k0[x], sq0);
            sq1 = fmaf(qv, k1[x], sq1);
            sb0 = fmaf(bv, g0[x], sb0);
            sb1 = fmaf(bv, g1[x], sb1);
        }
        // w0 = lane-r in [0,63-r]; w1 = 64+lane-r <= 100
        const bool ok0 = in0 && (lane >= r);
        const bool ok1 = in1 && (lane <= r + 36);
        // masked exp, no max-subtraction (validated R3-R13, absmax ~4e-3)
        const float e0 = ok0 ? __expf(sq0 * scale + sb0) : 0.f;
        const float e1 = ok1 ? __expf(sq1 * scale + sb1) : 0.f;

        if (lane >= r)      eww[lane - r]      = e0;
        if (lane <= r + 36) eww[64 + lane - r] = e1;
        // same-wave ds write->read is ordered — no barrier

        // PV with prob-sum folded into the butterfly
        float acc = 0.f, as = 0.f;
        #pragma unroll
        for (int it = 0; it < 25; ++it) {
            const int w = g + 4 * it;        // <= 99
            const float p = eww[w];
            acc = fmaf(p, vtw[(w + r) * 17 + d], acc);
            as += p;
        }
        if (g == 0) {
            const float p = eww[100];
            acc = fmaf(p, vtw[(100 + r) * 17 + d], acc);
            as += p;
        }
        acc += __shfl_xor(acc, 16); as += __shfl_xor(as, 16);
        acc += __shfl_xor(acc, 32); as += __shfl_xor(as, 32);
        if (lane < D) at[r * 132 + h * D + lane] = acc / as;
    }

    __syncthreads();   // at complete; vt dead -> reuse as split-K partials

    // ---- out-projection: split-K halves, Wo coalesced from global ----
    {
        float* part = &vt[0][0];             // [2][8][132]
        const int wh  = tid >> 8;            // k-half
        const int idx = tid & 255;
        const int c4  = idx & 31;
        const int row = idx >> 5;            // 0..7
        const int kb  = wh * 64;

        float4 acc = make_float4(0.f, 0.f, 0.f, 0.f);
        #pragma unroll 2
        for (int kk = 0; kk < 64; kk += 4) {
            const int k = kb + kk;
            const float4 w0 = ((const float4*)(Wo + (size_t)(k + 0) * E))[c4];
            const float4 w1 = ((const float4*)(Wo + (size_t)(k + 1) * E))[c4];
            const float4 w2 = ((const float4*)(Wo + (size_t)(k + 2) * E))[c4];
            const float4 w3 = ((const float4*)(Wo + (size_t)(k + 3) * E))[c4];
            const float4 x  = *(const float4*)&at[row * 132 + k];
            gemm_fma4(x, w0, w1, w2, w3, acc);
        }
        *(float4*)&part[(size_t)(wh * 8 + row) * 132 + c4 * 4] = acc;
        __syncthreads();

        if (tid < 256) {
            const int orow = tid >> 5, q = tid & 31;
            const float4 p0 = *(const float4*)&part[(size_t)orow * 132 + q * 4];
            const float4 p1 = *(const float4*)&part[(size_t)(8 + orow) * 132 + q * 4];
            const float4 bb = ((const float4*)bop)[q];
            *(float4*)(out + (size_t)(i0 + orow) * E + q * 4) =
                make_float4(p0.x + p1.x + bb.x, p0.y + p1.y + bb.y,
                            p0.z + p1.z + bb.z, p0.w + p1.w + bb.w);
        }
    }
}

// ---------------------------------------------------------------------------
extern "C" void kernel_launch(void* const* d_in, const int* in_sizes, int n_in,
                              void* d_out, int out_size, void* d_ws, size_t ws_size,
                              hipStream_t stream) {
    const float* query     = (const float*)d_in[0];
    const float* key       = (const float*)d_in[1];
    const float* value     = (const float*)d_in[2];
    const float* attn_bias = (const float*)d_in[3];
    const float* Wq  = (const float*)d_in[4];
    const float* bq  = (const float*)d_in[5];
    const float* Wk  = (const float*)d_in[6];
    const float* bk  = (const float*)d_in[7];
    const float* Wv  = (const float*)d_in[8];
    const float* bv  = (const float*)d_in[9];
    const float* Wo  = (const float*)d_in[10];
    const float* bo  = (const float*)d_in[11];
    const float* Wfe = (const float*)d_in[12];
    const float* bfe = (const float*)d_in[13];

    float* ws = (float*)d_ws;
    const int NE = N * E;
    float* qw = ws;
    float* kw = ws + 1 * NE;
    float* vw = ws + 2 * NE;
    float* bw = ws + 3 * NE;

    proj_kernel<<<3 * (N / 8), 128, 0, stream>>>(query, key, value, attn_bias,
                                                 Wq, bq, Wk, bk, Wv, bv,
                                                 Wfe, bfe, qw, kw, vw, bw);
    attn_out_kernel<<<N / 8, 512, 0, stream>>>(qw, kw, vw, bw, Wo, bo,
                                               (float*)d_out);
}

// Round 15
// 41.694 us; speedup vs baseline: 2.6355x; 1.0530x over previous
//
#include <hip/hip_runtime.h>
#include <math.h>

// Problem constants (fixed by the reference setup)
constexpr int N = 4096;
constexpr int E = 128;
constexpr int H = 8;
constexpr int D = 16;      // E / H
constexpr int SPAN = 50;

// ---------------------------------------------------------------------------
// Shared GEMM building blocks (R4 versions, verbatim).
// ---------------------------------------------------------------------------
__device__ __forceinline__ void gemm_fma4(const float4 x, const float4 w0,
                                          const float4 w1, const float4 w2,
                                          const float4 w3, float4& a)
{
    a.x = fmaf(x.x, w0.x, a.x); a.y = fmaf(x.x, w0.y, a.y);
    a.z = fmaf(x.x, w0.z, a.z); a.w = fmaf(x.x, w0.w, a.w);
    a.x = fmaf(x.y, w1.x, a.x); a.y = fmaf(x.y, w1.y, a.y);
    a.z = fmaf(x.y, w1.z, a.z); a.w = fmaf(x.y, w1.w, a.w);
    a.x = fmaf(x.z, w2.x, a.x); a.y = fmaf(x.z, w2.y, a.y);
    a.z = fmaf(x.z, w2.z, a.z); a.w = fmaf(x.z, w2.w, a.w);
    a.x = fmaf(x.w, w3.x, a.x); a.y = fmaf(x.w, w3.y, a.y);
    a.z = fmaf(x.w, w3.z, a.z); a.w = fmaf(x.w, w3.w, a.w);
}

__device__ __forceinline__ void gemm_half_8x128(
    const float* __restrict__ xs, const float* __restrict__ Wm,
    int h, int c4, int r0, float4 acc[4])
{
    const int kbase = h * 64;
    #pragma unroll 2
    for (int kk = 0; kk < 64; kk += 4) {
        const int k = kbase + kk;
        const float4 w0 = ((const float4*)(Wm + (size_t)(k + 0) * E))[c4];
        const float4 w1 = ((const float4*)(Wm + (size_t)(k + 1) * E))[c4];
        const float4 w2 = ((const float4*)(Wm + (size_t)(k + 2) * E))[c4];
        const float4 w3 = ((const float4*)(Wm + (size_t)(k + 3) * E))[c4];
        #pragma unroll
        for (int i = 0; i < 4; ++i) {
            const float4 x = *(const float4*)&xs[(r0 + i) * E + k];
            gemm_fma4(x, w0, w1, w2, w3, acc[i]);
        }
    }
}

__device__ __forceinline__ void combine_store(
    float* __restrict__ part, const float4 acc[4], int h, int c4, int r0,
    int tid, const float* __restrict__ bias, float* __restrict__ outp, int row0)
{
    #pragma unroll
    for (int i = 0; i < 4; ++i)
        *(float4*)&part[(size_t)(h * 8 + r0 + i) * 132 + c4 * 4] = acc[i];
    __syncthreads();
    #pragma unroll
    for (int rr = 0; rr < 2; ++rr) {
        const int idx = tid + 128 * rr;
        const int row = idx >> 5, q = idx & 31;
        const float4 p0 = *(const float4*)&part[(size_t)row * 132 + q * 4];
        const float4 p1 = *(const float4*)&part[(size_t)(8 + row) * 132 + q * 4];
        const float4 bb = ((const float4*)bias)[q];
        const float4 o  = make_float4(p0.x + p1.x + bb.x, p0.y + p1.y + bb.y,
                                      p0.z + p1.z + bb.z, p0.w + p1.w + bb.w);
        *(float4*)&outp[(size_t)(row0 + row) * E + q * 4] = o;
    }
    __syncthreads();
}

// ---------------------------------------------------------------------------
// Kernel 1: projections (R14 version, verbatim — one matrix per block).
// ---------------------------------------------------------------------------
__global__ __launch_bounds__(128) void proj_kernel(
    const float* __restrict__ query, const float* __restrict__ key,
    const float* __restrict__ value, const float* __restrict__ attn_bias,
    const float* __restrict__ Wq, const float* __restrict__ bq,
    const float* __restrict__ Wk, const float* __restrict__ bk,
    const float* __restrict__ Wv, const float* __restrict__ bv,
    const float* __restrict__ Wfe, const float* __restrict__ bfe,
    float* __restrict__ qo, float* __restrict__ ko,
    float* __restrict__ vo, float* __restrict__ bo_)
{
    __shared__ float xs[8][E];
    __shared__ float ab[8][8];
    __shared__ float part[2 * 8 * 132];

    const int tid  = threadIdx.x;
    const int c4   = tid & 31;
    const int r0   = ((tid >> 5) & 1) * 4;
    const int h    = tid >> 6;               // k-half
    const int bid  = blockIdx.x;
    const int mat  = bid >> 9;               // 0=q, 1=k, 2=v
    const int row0 = (bid & 511) * 8;

    const float* src  = mat == 0 ? query : (mat == 1 ? key : value);
    const float* Wm   = mat == 0 ? Wq : (mat == 1 ? Wk : Wv);
    const float* bias = mat == 0 ? bq : (mat == 1 ? bk : bv);
    float*       dst  = mat == 0 ? qo : (mat == 1 ? ko : vo);

    #pragma unroll
    for (int rr = 0; rr < 2; ++rr) {
        const int idx = tid + 128 * rr;
        const int row = idx >> 5, q = idx & 31;
        *(float4*)&xs[row][q * 4] =
            ((const float4*)(src + (size_t)(row0 + row) * E))[q];
    }
    if (mat == 0 && tid < 64) ab[tid >> 3][tid & 7] = attn_bias[(size_t)row0 * H + tid];
    __syncthreads();

    float4 acc[4];
    #pragma unroll
    for (int i = 0; i < 4; ++i) acc[i] = make_float4(0.f, 0.f, 0.f, 0.f);
    gemm_half_8x128(&xs[0][0], Wm, h, c4, r0, acc);
    combine_store(part, acc, h, c4, r0, tid, bias, dst, row0);

    if (mat == 0) {
        #pragma unroll
        for (int i = 0; i < 4; ++i) acc[i] = make_float4(0.f, 0.f, 0.f, 0.f);
        const float4 w0 = ((const float4*)(Wfe + (size_t)(h * 4 + 0) * E))[c4];
        const float4 w1 = ((const float4*)(Wfe + (size_t)(h * 4 + 1) * E))[c4];
        const float4 w2 = ((const float4*)(Wfe + (size_t)(h * 4 + 2) * E))[c4];
        const float4 w3 = ((const float4*)(Wfe + (size_t)(h * 4 + 3) * E))[c4];
        #pragma unroll
        for (int i = 0; i < 4; ++i) {
            const float4 x = *(const float4*)&ab[r0 + i][h * 4];
            gemm_fma4(x, w0, w1, w2, w3, acc[i]);
        }
        combine_store(part, acc, h, c4, r0, tid, bfe, bo_, row0);
    }
}

// ---------------------------------------------------------------------------
// Kernel 2: fused banded attention + output projection (R13 body) with
// XCD-AWARE BLOCK SWIZZLE (T1): work-id swz = (bid&7)*64 + bid>>3 gives each
// XCD a contiguous 64-tile chunk, so the 236-row k/v/b halo shared between
// neighboring tiles stays in that XCD's L2 instead of bouncing to L3.
// 512 % 8 == 0 -> mapping is bijective.
// ---------------------------------------------------------------------------
__global__ __launch_bounds__(512, 4) void attn_out_kernel(
    const float* __restrict__ qw, const float* __restrict__ kw,
    const float* __restrict__ vw, const float* __restrict__ bw,
    const float* __restrict__ Wo, const float* __restrict__ bop,
    float* __restrict__ out)
{
    __shared__ __align__(16) float vt[8][2176];   // per-wave V [128][17]
    __shared__ float ewb[8][104];                 // per-wave exp weights
    __shared__ float at[8 * 132];                 // attn tile [8][132]

    const int tid  = threadIdx.x;
    const int lane = tid & 63;
    const int h    = __builtin_amdgcn_readfirstlane(tid >> 6);  // head
    const int bid  = blockIdx.x;
    const int swz  = ((bid & 7) << 6) | (bid >> 3);   // XCD-contiguous chunks
    const int i0   = swz * 8;
    const int base = i0 - SPAN;

    float* vtw = &vt[h][0];
    float* eww = &ewb[h][0];

    // ---- stage V window for this head (per-wave, no barrier needed) ----
    {
        const int x4 = lane & 3, rr = lane >> 2;
        #pragma unroll
        for (int rep = 0; rep < 8; ++rep) {
            const int r = rep * 16 + rr;
            int j = base + r;
            j = j < 0 ? 0 : (j > N - 1 ? N - 1 : j);
            const float4 t = *(const float4*)(vw + (size_t)j * E + h * D + x4 * 4);
            vtw[r * 17 + x4 * 4 + 0] = t.x; vtw[r * 17 + x4 * 4 + 1] = t.y;
            vtw[r * 17 + x4 * 4 + 2] = t.z; vtw[r * 17 + x4 * 4 + 3] = t.w;
        }
    }

    // ---- K/B(feature) rows for this lane's two positions -> registers ----
    const int p0 = base + lane;
    const int p1 = p0 + 64;
    const bool in0 = (p0 >= 0) && (p0 < N);
    const bool in1 = (p1 < N);                // p1 >= 14 always
    const int c0 = p0 < 0 ? 0 : (p0 > N - 1 ? N - 1 : p0);
    const int c1 = p1 > N - 1 ? N - 1 : p1;

    float k0[16], k1[16], g0[16], g1[16];
    {
        const float4* kp0 = (const float4*)(kw + (size_t)c0 * E + h * D);
        const float4* kp1 = (const float4*)(kw + (size_t)c1 * E + h * D);
        const float4* gp0 = (const float4*)(bw + (size_t)c0 * E + h * D);
        const float4* gp1 = (const float4*)(bw + (size_t)c1 * E + h * D);
        #pragma unroll
        for (int x = 0; x < 4; ++x) {
            float4 t;
            t = kp0[x]; k0[4*x]=t.x; k0[4*x+1]=t.y; k0[4*x+2]=t.z; k0[4*x+3]=t.w;
            t = kp1[x]; k1[4*x]=t.x; k1[4*x+1]=t.y; k1[4*x+2]=t.z; k1[4*x+3]=t.w;
            t = gp0[x]; g0[4*x]=t.x; g0[4*x+1]=t.y; g0[4*x+2]=t.z; g0[4*x+3]=t.w;
            t = gp1[x]; g1[4*x]=t.x; g1[4*x+1]=t.y; g1[4*x+2]=t.z; g1[4*x+3]=t.w;
        }
    }

    const float scale = 1.0f / 64.0f;        // 1/sqrt(4096)
    const int d = lane & 15;
    const int g = lane >> 4;

    for (int r = 0; r < 8; ++r) {
        // Q and B(query) rows: wave-uniform addresses -> scalar loads
        const float* qp = qw + (size_t)(i0 + r) * E + h * D;
        const float* bp = bw + (size_t)(i0 + r) * E + h * D;

        float sq0 = 0.f, sq1 = 0.f, sb0 = 0.f, sb1 = 0.f;
        #pragma unroll
        for (int x = 0; x < 16; ++x) {
            const float qv = qp[x];
            const float bv = bp[x];
            sq0 = fmaf(qv, k0[x], sq0);
            sq1 = fmaf(qv, k1[x], sq1);
            sb0 = fmaf(bv, g0[x], sb0);
            sb1 = fmaf(bv, g1[x], sb1);
        }
        // w0 = lane-r in [0,63-r]; w1 = 64+lane-r <= 100
        const bool ok0 = in0 && (lane >= r);
        const bool ok1 = in1 && (lane <= r + 36);
        // masked exp, no max-subtraction (validated R3-R14, absmax ~4e-3)
        const float e0 = ok0 ? __expf(sq0 * scale + sb0) : 0.f;
        const float e1 = ok1 ? __expf(sq1 * scale + sb1) : 0.f;

        if (lane >= r)      eww[lane - r]      = e0;
        if (lane <= r + 36) eww[64 + lane - r] = e1;
        // same-wave ds write->read is ordered — no barrier

        // PV with prob-sum folded into the butterfly
        float acc = 0.f, as = 0.f;
        #pragma unroll
        for (int it = 0; it < 25; ++it) {
            const int w = g + 4 * it;        // <= 99
            const float p = eww[w];
            acc = fmaf(p, vtw[(w + r) * 17 + d], acc);
            as += p;
        }
        if (g == 0) {
            const float p = eww[100];
            acc = fmaf(p, vtw[(100 + r) * 17 + d], acc);
            as += p;
        }
        acc += __shfl_xor(acc, 16); as += __shfl_xor(as, 16);
        acc += __shfl_xor(acc, 32); as += __shfl_xor(as, 32);
        if (lane < D) at[r * 132 + h * D + lane] = acc / as;
    }

    __syncthreads();   // at complete; vt dead -> reuse as split-K partials

    // ---- out-projection: split-K halves, Wo coalesced from global ----
    {
        float* part = &vt[0][0];             // [2][8][132]
        const int wh  = tid >> 8;            // k-half
        const int idx = tid & 255;
        const int c4  = idx & 31;
        const int row = idx >> 5;            // 0..7
        const int kb  = wh * 64;

        float4 acc = make_float4(0.f, 0.f, 0.f, 0.f);
        #pragma unroll 2
        for (int kk = 0; kk < 64; kk += 4) {
            const int k = kb + kk;
            const float4 w0 = ((const float4*)(Wo + (size_t)(k + 0) * E))[c4];
            const float4 w1 = ((const float4*)(Wo + (size_t)(k + 1) * E))[c4];
            const float4 w2 = ((const float4*)(Wo + (size_t)(k + 2) * E))[c4];
            const float4 w3 = ((const float4*)(Wo + (size_t)(k + 3) * E))[c4];
            const float4 x  = *(const float4*)&at[row * 132 + k];
            gemm_fma4(x, w0, w1, w2, w3, acc);
        }
        *(float4*)&part[(size_t)(wh * 8 + row) * 132 + c4 * 4] = acc;
        __syncthreads();

        if (tid < 256) {
            const int orow = tid >> 5, q = tid & 31;
            const float4 p0 = *(const float4*)&part[(size_t)orow * 132 + q * 4];
            const float4 p1 = *(const float4*)&part[(size_t)(8 + orow) * 132 + q * 4];
            const float4 bb = ((const float4*)bop)[q];
            *(float4*)(out + (size_t)(i0 + orow) * E + q * 4) =
                make_float4(p0.x + p1.x + bb.x, p0.y + p1.y + bb.y,
                            p0.z + p1.z + bb.z, p0.w + p1.w + bb.w);
        }
    }
}

// ---------------------------------------------------------------------------
extern "C" void kernel_launch(void* const* d_in, const int* in_sizes, int n_in,
                              void* d_out, int out_size, void* d_ws, size_t ws_size,
                              hipStream_t stream) {
    const float* query     = (const float*)d_in[0];
    const float* key       = (const float*)d_in[1];
    const float* value     = (const float*)d_in[2];
    const float* attn_bias = (const float*)d_in[3];
    const float* Wq  = (const float*)d_in[4];
    const float* bq  = (const float*)d_in[5];
    const float* Wk  = (const float*)d_in[6];
    const float* bk  = (const float*)d_in[7];
    const float* Wv  = (const float*)d_in[8];
    const float* bv  = (const float*)d_in[9];
    const float* Wo  = (const float*)d_in[10];
    const float* bo  = (const float*)d_in[11];
    const float* Wfe = (const float*)d_in[12];
    const float* bfe = (const float*)d_in[13];

    float* ws = (float*)d_ws;
    const int NE = N * E;
    float* qw = ws;
    float* kw = ws + 1 * NE;
    float* vw = ws + 2 * NE;
    float* bw = ws + 3 * NE;

    proj_kernel<<<3 * (N / 8), 128, 0, stream>>>(query, key, value, attn_bias,
                                                 Wq, bq, Wk, bk, Wv, bv,
                                                 Wfe, bfe, qw, kw, vw, bw);
    attn_out_kernel<<<N / 8, 512, 0, stream>>>(qw, kw, vw, bw, Wo, bo,
                                               (float*)d_out);
}

// Round 16
// 40.821 us; speedup vs baseline: 2.6919x; 1.0214x over previous
//
#include <hip/hip_runtime.h>
#include <math.h>

// Problem constants (fixed by the reference setup)
constexpr int N = 4096;
constexpr int E = 128;
constexpr int H = 8;
constexpr int D = 16;      // E / H
constexpr int SPAN = 50;

// 16 FMAs: a[c] += x[j] * wj[c]
__device__ __forceinline__ void gemm_fma4(const float4 x, const float4 w0,
                                          const float4 w1, const float4 w2,
                                          const float4 w3, float4& a)
{
    a.x = fmaf(x.x, w0.x, a.x); a.y = fmaf(x.x, w0.y, a.y);
    a.z = fmaf(x.x, w0.z, a.z); a.w = fmaf(x.x, w0.w, a.w);
    a.x = fmaf(x.y, w1.x, a.x); a.y = fmaf(x.y, w1.y, a.y);
    a.z = fmaf(x.y, w1.z, a.z); a.w = fmaf(x.y, w1.w, a.w);
    a.x = fmaf(x.z, w2.x, a.x); a.y = fmaf(x.z, w2.y, a.y);
    a.z = fmaf(x.z, w2.z, a.z); a.w = fmaf(x.z, w2.w, a.w);
    a.x = fmaf(x.w, w3.x, a.x); a.y = fmaf(x.w, w3.y, a.y);
    a.z = fmaf(x.w, w3.z, a.z); a.w = fmaf(x.w, w3.w, a.w);
}

// ---------------------------------------------------------------------------
// Kernel 1: projections — 16-ROW TILES (halves W traffic vs R14's 8-row).
// 256 threads = (c4: 32 col-quads) x (rg: 4 row-groups) x (kh: 2 k-halves).
// Thread computes 4 rows {rg, rg+4, rg+8, rg+12} x 4 cols over its k-half;
// halves combined through LDS. Grid = 3 mats x 256 = 768 blocks = 3072 waves
// (3 waves/SIMD — same occupancy as R14, traffic is the only variable).
// mat==0 blocks also compute the (K=8) feature projection (kh-split 4/4).
// ---------------------------------------------------------------------------
__global__ __launch_bounds__(256) void proj_kernel(
    const float* __restrict__ query, const float* __restrict__ key,
    const float* __restrict__ value, const float* __restrict__ attn_bias,
    const float* __restrict__ Wq, const float* __restrict__ bq,
    const float* __restrict__ Wk, const float* __restrict__ bk,
    const float* __restrict__ Wv, const float* __restrict__ bv,
    const float* __restrict__ Wfe, const float* __restrict__ bfe,
    float* __restrict__ qo, float* __restrict__ ko,
    float* __restrict__ vo, float* __restrict__ bo_)
{
    __shared__ __align__(16) float xs[16 * 128];
    __shared__ __align__(16) float ab[16 * 8];
    __shared__ __align__(16) float part[2 * 16 * 132];

    const int tid  = threadIdx.x;
    const int c4   = tid & 31;
    const int rg   = (tid >> 5) & 3;
    const int kh   = tid >> 7;
    const int bid  = blockIdx.x;
    const int mat  = bid >> 8;               // 0=q, 1=k, 2=v
    const int row0 = (bid & 255) * 16;

    const float* src  = mat == 0 ? query : (mat == 1 ? key : value);
    const float* Wm   = mat == 0 ? Wq : (mat == 1 ? Wk : Wv);
    const float* bias = mat == 0 ? bq : (mat == 1 ? bk : bv);
    float*       dst  = mat == 0 ? qo : (mat == 1 ? ko : vo);

    // stage the 16x128 X tile (2 coalesced float4 per thread)
    #pragma unroll
    for (int rr = 0; rr < 2; ++rr) {
        const int idx = tid + 256 * rr;
        const int row = idx >> 5, q = idx & 31;
        *(float4*)&xs[row * 128 + q * 4] =
            ((const float4*)(src + (size_t)(row0 + row) * E))[q];
    }
    if (mat == 0 && tid < 128) ab[tid] = attn_bias[(size_t)row0 * H + tid];
    __syncthreads();

    const int kb = kh * 64;
    {
        float4 acc[4];
        #pragma unroll
        for (int i = 0; i < 4; ++i) acc[i] = make_float4(0.f, 0.f, 0.f, 0.f);

        #pragma unroll 2
        for (int kk = 0; kk < 64; kk += 4) {
            const int k = kb + kk;
            const float4 w0 = ((const float4*)(Wm + (size_t)(k + 0) * E))[c4];
            const float4 w1 = ((const float4*)(Wm + (size_t)(k + 1) * E))[c4];
            const float4 w2 = ((const float4*)(Wm + (size_t)(k + 2) * E))[c4];
            const float4 w3 = ((const float4*)(Wm + (size_t)(k + 3) * E))[c4];
            const float4 x0 = *(const float4*)&xs[(rg +  0) * 128 + k];
            const float4 x1 = *(const float4*)&xs[(rg +  4) * 128 + k];
            const float4 x2 = *(const float4*)&xs[(rg +  8) * 128 + k];
            const float4 x3 = *(const float4*)&xs[(rg + 12) * 128 + k];
            gemm_fma4(x0, w0, w1, w2, w3, acc[0]);
            gemm_fma4(x1, w0, w1, w2, w3, acc[1]);
            gemm_fma4(x2, w0, w1, w2, w3, acc[2]);
            gemm_fma4(x3, w0, w1, w2, w3, acc[3]);
        }
        #pragma unroll
        for (int i = 0; i < 4; ++i)
            *(float4*)&part[(size_t)(kh * 16 + rg + 4 * i) * 132 + c4 * 4] = acc[i];
        __syncthreads();
        #pragma unroll
        for (int u = 0; u < 2; ++u) {
            const int o = tid + 256 * u;      // 512 float4 outputs
            const int row = o >> 5, q = o & 31;
            const float4 p0 = *(const float4*)&part[(size_t)row * 132 + q * 4];
            const float4 p1 = *(const float4*)&part[(size_t)(16 + row) * 132 + q * 4];
            const float4 bb = ((const float4*)bias)[q];
            *(float4*)(dst + (size_t)(row0 + row) * E + q * 4) =
                make_float4(p0.x + p1.x + bb.x, p0.y + p1.y + bb.y,
                            p0.z + p1.z + bb.z, p0.w + p1.w + bb.w);
        }
    }

    if (mat == 0) {
        // feature projection: b = attn_bias @ Wfe + bfe  (K=8, kh-split 4/4)
        __syncthreads();
        float4 acc[4];
        #pragma unroll
        for (int i = 0; i < 4; ++i) acc[i] = make_float4(0.f, 0.f, 0.f, 0.f);
        const float4 w0 = ((const float4*)(Wfe + (size_t)(kh * 4 + 0) * E))[c4];
        const float4 w1 = ((const float4*)(Wfe + (size_t)(kh * 4 + 1) * E))[c4];
        const float4 w2 = ((const float4*)(Wfe + (size_t)(kh * 4 + 2) * E))[c4];
        const float4 w3 = ((const float4*)(Wfe + (size_t)(kh * 4 + 3) * E))[c4];
        #pragma unroll
        for (int i = 0; i < 4; ++i) {
            const float4 x = *(const float4*)&ab[(rg + 4 * i) * 8 + kh * 4];
            gemm_fma4(x, w0, w1, w2, w3, acc[i]);
        }
        #pragma unroll
        for (int i = 0; i < 4; ++i)
            *(float4*)&part[(size_t)(kh * 16 + rg + 4 * i) * 132 + c4 * 4] = acc[i];
        __syncthreads();
        #pragma unroll
        for (int u = 0; u < 2; ++u) {
            const int o = tid + 256 * u;
            const int row = o >> 5, q = o & 31;
            const float4 p0 = *(const float4*)&part[(size_t)row * 132 + q * 4];
            const float4 p1 = *(const float4*)&part[(size_t)(16 + row) * 132 + q * 4];
            const float4 bb = ((const float4*)bfe)[q];
            *(float4*)(bo_ + (size_t)(row0 + row) * E + q * 4) =
                make_float4(p0.x + p1.x + bb.x, p0.y + p1.y + bb.y,
                            p0.z + p1.z + bb.z, p0.w + p1.w + bb.w);
        }
    }
}

// ---------------------------------------------------------------------------
// Kernel 2: fused banded attention + output projection (R15 version with
// XCD-aware swizzle, verbatim — the 41.7us config).
// ---------------------------------------------------------------------------
__global__ __launch_bounds__(512, 4) void attn_out_kernel(
    const float* __restrict__ qw, const float* __restrict__ kw,
    const float* __restrict__ vw, const float* __restrict__ bw,
    const float* __restrict__ Wo, const float* __restrict__ bop,
    float* __restrict__ out)
{
    __shared__ __align__(16) float vt[8][2176];   // per-wave V [128][17]
    __shared__ float ewb[8][104];                 // per-wave exp weights
    __shared__ float at[8 * 132];                 // attn tile [8][132]

    const int tid  = threadIdx.x;
    const int lane = tid & 63;
    const int h    = __builtin_amdgcn_readfirstlane(tid >> 6);  // head
    const int bid  = blockIdx.x;
    const int swz  = ((bid & 7) << 6) | (bid >> 3);   // XCD-contiguous chunks
    const int i0   = swz * 8;
    const int base = i0 - SPAN;

    float* vtw = &vt[h][0];
    float* eww = &ewb[h][0];

    // ---- stage V window for this head (per-wave, no barrier needed) ----
    {
        const int x4 = lane & 3, rr = lane >> 2;
        #pragma unroll
        for (int rep = 0; rep < 8; ++rep) {
            const int r = rep * 16 + rr;
            int j = base + r;
            j = j < 0 ? 0 : (j > N - 1 ? N - 1 : j);
            const float4 t = *(const float4*)(vw + (size_t)j * E + h * D + x4 * 4);
            vtw[r * 17 + x4 * 4 + 0] = t.x; vtw[r * 17 + x4 * 4 + 1] = t.y;
            vtw[r * 17 + x4 * 4 + 2] = t.z; vtw[r * 17 + x4 * 4 + 3] = t.w;
        }
    }

    // ---- K/B(feature) rows for this lane's two positions -> registers ----
    const int p0 = base + lane;
    const int p1 = p0 + 64;
    const bool in0 = (p0 >= 0) && (p0 < N);
    const bool in1 = (p1 < N);                // p1 >= 14 always
    const int c0 = p0 < 0 ? 0 : (p0 > N - 1 ? N - 1 : p0);
    const int c1 = p1 > N - 1 ? N - 1 : p1;

    float k0[16], k1[16], g0[16], g1[16];
    {
        const float4* kp0 = (const float4*)(kw + (size_t)c0 * E + h * D);
        const float4* kp1 = (const float4*)(kw + (size_t)c1 * E + h * D);
        const float4* gp0 = (const float4*)(bw + (size_t)c0 * E + h * D);
        const float4* gp1 = (const float4*)(bw + (size_t)c1 * E + h * D);
        #pragma unroll
        for (int x = 0; x < 4; ++x) {
            float4 t;
            t = kp0[x]; k0[4*x]=t.x; k0[4*x+1]=t.y; k0[4*x+2]=t.z; k0[4*x+3]=t.w;
            t = kp1[x]; k1[4*x]=t.x; k1[4*x+1]=t.y; k1[4*x+2]=t.z; k1[4*x+3]=t.w;
            t = gp0[x]; g0[4*x]=t.x; g0[4*x+1]=t.y; g0[4*x+2]=t.z; g0[4*x+3]=t.w;
            t = gp1[x]; g1[4*x]=t.x; g1[4*x+1]=t.y; g1[4*x+2]=t.z; g1[4*x+3]=t.w;
        }
    }

    const float scale = 1.0f / 64.0f;        // 1/sqrt(4096)
    const int d = lane & 15;
    const int g = lane >> 4;

    for (int r = 0; r < 8; ++r) {
        // Q and B(query) rows: wave-uniform addresses -> scalar loads
        const float* qp = qw + (size_t)(i0 + r) * E + h * D;
        const float* bp = bw + (size_t)(i0 + r) * E + h * D;

        float sq0 = 0.f, sq1 = 0.f, sb0 = 0.f, sb1 = 0.f;
        #pragma unroll
        for (int x = 0; x < 16; ++x) {
            const float qv = qp[x];
            const float bv = bp[x];
            sq0 = fmaf(qv, k0[x], sq0);
            sq1 = fmaf(qv, k1[x], sq1);
            sb0 = fmaf(bv, g0[x], sb0);
            sb1 = fmaf(bv, g1[x], sb1);
        }
        // w0 = lane-r in [0,63-r]; w1 = 64+lane-r <= 100
        const bool ok0 = in0 && (lane >= r);
        const bool ok1 = in1 && (lane <= r + 36);
        // masked exp, no max-subtraction (validated R3-R15, absmax ~4e-3)
        const float e0 = ok0 ? __expf(sq0 * scale + sb0) : 0.f;
        const float e1 = ok1 ? __expf(sq1 * scale + sb1) : 0.f;

        if (lane >= r)      eww[lane - r]      = e0;
        if (lane <= r + 36) eww[64 + lane - r] = e1;
        // same-wave ds write->read is ordered — no barrier

        // PV with prob-sum folded into the butterfly
        float acc = 0.f, as = 0.f;
        #pragma unroll
        for (int it = 0; it < 25; ++it) {
            const int w = g + 4 * it;        // <= 99
            const float p = eww[w];
            acc = fmaf(p, vtw[(w + r) * 17 + d], acc);
            as += p;
        }
        if (g == 0) {
            const float p = eww[100];
            acc = fmaf(p, vtw[(100 + r) * 17 + d], acc);
            as += p;
        }
        acc += __shfl_xor(acc, 16); as += __shfl_xor(as, 16);
        acc += __shfl_xor(acc, 32); as += __shfl_xor(as, 32);
        if (lane < D) at[r * 132 + h * D + lane] = acc / as;
    }

    __syncthreads();   // at complete; vt dead -> reuse as split-K partials

    // ---- out-projection: split-K halves, Wo coalesced from global ----
    {
        float* part = &vt[0][0];             // [2][8][132]
        const int wh  = tid >> 8;            // k-half
        const int idx = tid & 255;
        const int c4  = idx & 31;
        const int row = idx >> 5;            // 0..7
        const int kb  = wh * 64;

        float4 acc = make_float4(0.f, 0.f, 0.f, 0.f);
        #pragma unroll 2
        for (int kk = 0; kk < 64; kk += 4) {
            const int k = kb + kk;
            const float4 w0 = ((const float4*)(Wo + (size_t)(k + 0) * E))[c4];
            const float4 w1 = ((const float4*)(Wo + (size_t)(k + 1) * E))[c4];
            const float4 w2 = ((const float4*)(Wo + (size_t)(k + 2) * E))[c4];
            const float4 w3 = ((const float4*)(Wo + (size_t)(k + 3) * E))[c4];
            const float4 x  = *(const float4*)&at[row * 132 + k];
            gemm_fma4(x, w0, w1, w2, w3, acc);
        }
        *(float4*)&part[(size_t)(wh * 8 + row) * 132 + c4 * 4] = acc;
        __syncthreads();

        if (tid < 256) {
            const int orow = tid >> 5, q = tid & 31;
            const float4 p0 = *(const float4*)&part[(size_t)orow * 132 + q * 4];
            const float4 p1 = *(const float4*)&part[(size_t)(8 + orow) * 132 + q * 4];
            const float4 bb = ((const float4*)bop)[q];
            *(float4*)(out + (size_t)(i0 + orow) * E + q * 4) =
                make_float4(p0.x + p1.x + bb.x, p0.y + p1.y + bb.y,
                            p0.z + p1.z + bb.z, p0.w + p1.w + bb.w);
        }
    }
}

// ---------------------------------------------------------------------------
extern "C" void kernel_launch(void* const* d_in, const int* in_sizes, int n_in,
                              void* d_out, int out_size, void* d_ws, size_t ws_size,
                              hipStream_t stream) {
    const float* query     = (const float*)d_in[0];
    const float* key       = (const float*)d_in[1];
    const float* value     = (const float*)d_in[2];
    const float* attn_bias = (const float*)d_in[3];
    const float* Wq  = (const float*)d_in[4];
    const float* bq  = (const float*)d_in[5];
    const float* Wk  = (const float*)d_in[6];
    const float* bk  = (const float*)d_in[7];
    const float* Wv  = (const float*)d_in[8];
    const float* bv  = (const float*)d_in[9];
    const float* Wo  = (const float*)d_in[10];
    const float* bo  = (const float*)d_in[11];
    const float* Wfe = (const float*)d_in[12];
    const float* bfe = (const float*)d_in[13];

    float* ws = (float*)d_ws;
    const int NE = N * E;
    float* qw = ws;
    float* kw = ws + 1 * NE;
    float* vw = ws + 2 * NE;
    float* bw = ws + 3 * NE;

    proj_kernel<<<3 * 256, 256, 0, stream>>>(query, key, value, attn_bias,
                                             Wq, bq, Wk, bk, Wv, bv,
                                             Wfe, bfe, qw, kw, vw, bw);
    attn_out_kernel<<<N / 8, 512, 0, stream>>>(qw, kw, vw, bw, Wo, bo,
                                               (float*)d_out);
}